// Round 1
// baseline (623.134 us; speedup 1.0000x reference)
//
#include <hip/hip_runtime.h>
#include <hip/hip_bf16.h>
#include <cstdio>

// Problem constants: B=64, T=2048, D=256, U=256 (fp32 in/out)
#define BB 64
#define TT 2048
#define DD 256
#define UU 256
#define MM (BB*TT)          // 131072 GEMM rows
#define NN (3*UU)           // 768 fused output cols (z,r,h)
#define PLANE ((size_t)BB*TT*UU)   // 33554432 elements per projection plane

typedef _Float16 half8 __attribute__((ext_vector_type(8)));
typedef float floatx4 __attribute__((ext_vector_type(4)));

// ---------------- fast math helpers ----------------
__device__ inline float fexp2(float x){
#if __has_builtin(__builtin_amdgcn_exp2f)
  return __builtin_amdgcn_exp2f(x);
#else
  return exp2f(x);
#endif
}
__device__ inline float frcp(float x){
#if __has_builtin(__builtin_amdgcn_rcpf)
  return __builtin_amdgcn_rcpf(x);
#else
  return 1.0f/x;
#endif
}
// tanh(a) = 1 - 2/(exp2(2*log2e*a)+1)  (saturates correctly at +-inf)
__device__ inline float ftanh(float a){
  const float TWO_L2E = 2.8853900817779268f;
  return 1.0f - 2.0f*frcp(fexp2(TWO_L2E*a) + 1.0f);
}
__device__ inline float fsigmoid(float a){
  const float L2E = 1.4426950408889634f;
  return frcp(1.0f + fexp2(-L2E*a));
}

// ---------------- kernel 0: weights -> fused transposed f16 [N=768][K=256] ----------------
__global__ __launch_bounds__(256) void prep_kernel(const float* __restrict__ kz,
                                                   const float* __restrict__ kr,
                                                   const float* __restrict__ kh,
                                                   _Float16* __restrict__ K16T){
  int o = blockIdx.x*256 + threadIdx.x;     // 0..196607
  int n = o >> 8;                            // fused col: p*256+u
  int k = o & 255;                           // d
  int p = n >> 8;
  int u = n & 255;
  const float* w = (p==0) ? kz : ((p==1) ? kr : kh);
  K16T[o] = (_Float16)w[k*UU + u];
}

// ---------------- kernel 1: GEMM  P[p][(b,t)][u] = x @ K + bias  (f16 out) ----------------
#define BM 128
#define BN 128
#define BK 32
#define LDA 40   // padded f16 row stride for As (80B: 16B aligned, bank-spread)

__global__ __launch_bounds__(256) void gemm_kernel(const float* __restrict__ X,
                                                   const _Float16* __restrict__ K16T,
                                                   const float* __restrict__ bz,
                                                   const float* __restrict__ br,
                                                   const float* __restrict__ bh,
                                                   _Float16* __restrict__ P){
  __shared__ __align__(16) _Float16 As[BM*LDA];  // 10240 B, [m][k] k-contig
  __shared__ __align__(16) _Float16 Bs[BN*BK];   // 8192 B,  [n][k] k-contig
  const int tid = threadIdx.x;
  const int bx = blockIdx.x;        // 0..5  (N tiles)
  const int by = blockIdx.y;        // 0..1023 (M tiles)
  const int rowBase = by*BM;
  const int nBase = bx*BN;

  const int wave = tid >> 6, lane = tid & 63;
  const int wm = wave & 1, wn = wave >> 1;     // 2x2 wave grid, each 64x64
  const int lrow = lane & 15, lkq = lane >> 4; // frag row / k-quad

  floatx4 acc[4][4] = {};

  // A staging: thread covers row tid>>1, 16 cols at (tid&1)*16
  const int arow = tid >> 1;
  const int acol = (tid & 1) * 16;
  const float* aptr = X + (size_t)(rowBase + arow)*DD + acol;
  _Float16* asdst = &As[arow*LDA + acol];

  for (int k0 = 0; k0 < DD; k0 += BK) {
    __syncthreads();   // protect LDS from previous iteration's readers
    // --- B tile: async global->LDS (f16, 2 x 16B per thread) ---
    #pragma unroll
    for (int i = 0; i < 2; i++) {
      int c = i*256 + tid;                 // chunk id, 512 chunks x 16B = 8KB
      const _Float16* g = K16T + (size_t)(nBase + (c>>2))*DD + k0 + (c&3)*8;
      __builtin_amdgcn_global_load_lds(
          (const __attribute__((address_space(1))) void*)g,
          (__attribute__((address_space(3))) void*)(Bs + c*8),
          16, 0, 0);
    }
    // --- A tile: fp32 load -> f16 cvt -> LDS ---
    floatx4 a0 = *(const floatx4*)(aptr + k0);
    floatx4 a1 = *(const floatx4*)(aptr + k0 + 4);
    floatx4 a2 = *(const floatx4*)(aptr + k0 + 8);
    floatx4 a3 = *(const floatx4*)(aptr + k0 + 12);
    half8 pk0, pk1;
    #pragma unroll
    for (int q = 0; q < 4; q++){
      pk0[q]   = (_Float16)a0[q];
      pk0[4+q] = (_Float16)a1[q];
      pk1[q]   = (_Float16)a2[q];
      pk1[4+q] = (_Float16)a3[q];
    }
    *(half8*)asdst       = pk0;
    *(half8*)(asdst + 8) = pk1;
    __syncthreads();
    // --- fragments + MFMA (BK=32 == one K step) ---
    half8 af[4], bf[4];
    #pragma unroll
    for (int i = 0; i < 4; i++)
      af[i] = *(const half8*)&As[(wm*64 + i*16 + lrow)*LDA + lkq*8];
    #pragma unroll
    for (int j = 0; j < 4; j++)
      bf[j] = *(const half8*)&Bs[(wn*64 + j*16 + lrow)*BK + lkq*8];
    #pragma unroll
    for (int i = 0; i < 4; i++)
      #pragma unroll
      for (int j = 0; j < 4; j++)
        acc[i][j] = __builtin_amdgcn_mfma_f32_16x16x32_f16(af[i], bf[j], acc[i][j], 0, 0, 0);
  }

  // --- epilogue: add bias, f16 store into plane p ---
  const int p = bx >> 1;                // plane (z/r/h); BN=128 never crosses planes
  const int ub = (bx & 1) * 128;        // u base within plane
  const float* bias = (p==0) ? bz : ((p==1) ? br : bh);
  _Float16* Pp = P + (size_t)p * PLANE;
  #pragma unroll
  for (int j = 0; j < 4; j++){
    int col = ub + wn*64 + j*16 + lrow;           // u  (C/D: col = lane&15)
    float bv = bias[col];
    #pragma unroll
    for (int i = 0; i < 4; i++){
      #pragma unroll
      for (int r = 0; r < 4; r++){
        int grow = rowBase + wm*64 + i*16 + lkq*4 + r;   // row = quad*4+reg
        Pp[(size_t)grow*UU + col] = (_Float16)(acc[i][j][r] + bv);
      }
    }
  }
}

// ---------------- kernel 2: time scan, one lane per (b,u) ----------------
#define PF 16
__global__ __launch_bounds__(64) void scan_kernel(const _Float16* __restrict__ P,
                                                  const float* __restrict__ mz,
                                                  const float* __restrict__ mr,
                                                  float* __restrict__ out){
  const int b = blockIdx.x >> 2;
  const int u = ((blockIdx.x & 3) << 6) | threadIdx.x;
  const size_t base0 = (size_t)b * (TT*UU) + u;
  const _Float16* pz = P + base0;
  const _Float16* pr = P + PLANE + base0;
  const _Float16* ph = P + 2*PLANE + base0;
  float* po = out + base0;
  const float vmz = mz[u], vmr = mr[u];
  float h = 0.0f;

  _Float16 qz[2][PF], qr[2][PF], qh[2][PF];
  #pragma unroll
  for (int i = 0; i < PF; i++){
    qz[0][i] = pz[(size_t)i*UU]; qr[0][i] = pr[(size_t)i*UU]; qh[0][i] = ph[(size_t)i*UU];
  }
  #pragma unroll
  for (int i = 0; i < PF; i++){
    qz[1][i] = pz[(size_t)(PF+i)*UU]; qr[1][i] = pr[(size_t)(PF+i)*UU]; qh[1][i] = ph[(size_t)(PF+i)*UU];
  }

  const int NC = TT/PF;   // 128 chunks
  for (int c = 0; c < NC; c += 2){
    // process buffer 0 (chunk c)
    #pragma unroll
    for (int i = 0; i < PF; i++){
      float xz = (float)qz[0][i], xr = (float)qr[0][i], xh = (float)qh[0][i];
      float r  = ftanh(xr + h*vmr) + 1.0f;
      float z  = fsigmoid(xz + h*vmz);
      float hh = ftanh(xh + r*h);
      h = (1.0f - z)*hh + z*h;
      po[(size_t)(c*PF + i)*UU] = h;
    }
    if (c + 2 < NC){
      size_t off = (size_t)(c+2)*PF*UU;
      #pragma unroll
      for (int i = 0; i < PF; i++){
        qz[0][i] = pz[off + (size_t)i*UU]; qr[0][i] = pr[off + (size_t)i*UU]; qh[0][i] = ph[off + (size_t)i*UU];
      }
    }
    // process buffer 1 (chunk c+1)
    #pragma unroll
    for (int i = 0; i < PF; i++){
      float xz = (float)qz[1][i], xr = (float)qr[1][i], xh = (float)qh[1][i];
      float r  = ftanh(xr + h*vmr) + 1.0f;
      float z  = fsigmoid(xz + h*vmz);
      float hh = ftanh(xh + r*h);
      h = (1.0f - z)*hh + z*h;
      po[(size_t)((c+1)*PF + i)*UU] = h;
    }
    if (c + 3 < NC){
      size_t off = (size_t)(c+3)*PF*UU;
      #pragma unroll
      for (int i = 0; i < PF; i++){
        qz[1][i] = pz[off + (size_t)i*UU]; qr[1][i] = pr[off + (size_t)i*UU]; qh[1][i] = ph[off + (size_t)i*UU];
      }
    }
  }
}

extern "C" void kernel_launch(void* const* d_in, const int* in_sizes, int n_in,
                              void* d_out, int out_size, void* d_ws, size_t ws_size,
                              hipStream_t stream) {
  (void)in_sizes; (void)n_in; (void)out_size;
  const float* x  = (const float*)d_in[0];
  const float* kz = (const float*)d_in[1];
  const float* kr = (const float*)d_in[2];
  const float* kh = (const float*)d_in[3];
  const float* mz = (const float*)d_in[4];
  const float* mr = (const float*)d_in[5];
  const float* bz = (const float*)d_in[6];
  const float* br = (const float*)d_in[7];
  const float* bh = (const float*)d_in[8];
  float* out = (float*)d_out;

  // ws layout: [K16T: 768*256 f16 = 393216 B][P: 3 planes * 33554432 f16 = 201326592 B]
  _Float16* K16T = (_Float16*)d_ws;
  _Float16* P    = (_Float16*)((char*)d_ws + 393216);
  fprintf(stderr, "[bru] ws_size=%zu need=%zu\n", ws_size, (size_t)(393216 + 3*PLANE*2));

  hipLaunchKernelGGL(prep_kernel, dim3(NN*DD/256), dim3(256), 0, stream, kz, kr, kh, K16T);
  hipLaunchKernelGGL(gemm_kernel, dim3(NN/BN, MM/BM), dim3(256), 0, stream,
                     x, K16T, bz, br, bh, P);
  hipLaunchKernelGGL(scan_kernel, dim3(256), dim3(64), 0, stream, P, mz, mr, out);
}

// Round 2
// 467.238 us; speedup vs baseline: 1.3337x; 1.3337x over previous
//
#include <hip/hip_runtime.h>
#include <hip/hip_bf16.h>

// Problem constants: B=64, T=2048, D=256, U=256 (fp32 in/out)
#define BB 64
#define TT 2048
#define DD 256
#define UU 256
#define MM (BB*TT)          // 131072 GEMM rows
#define NN (3*UU)           // 768 fused output cols (z,r,h)
#define PLANE ((size_t)BB*TT*UU)   // 33554432 elements per projection plane

typedef _Float16 half8 __attribute__((ext_vector_type(8)));
typedef _Float16 half4 __attribute__((ext_vector_type(4)));
typedef float floatx4 __attribute__((ext_vector_type(4)));

// ---------------- fast math helpers ----------------
__device__ inline float fexp2(float x){
#if __has_builtin(__builtin_amdgcn_exp2f)
  return __builtin_amdgcn_exp2f(x);
#else
  return exp2f(x);
#endif
}
__device__ inline float frcp(float x){
#if __has_builtin(__builtin_amdgcn_rcpf)
  return __builtin_amdgcn_rcpf(x);
#else
  return 1.0f/x;
#endif
}
// tanh(a) = 1 - 2/(exp2(2*log2e*a)+1)  (saturates correctly at +-inf)
__device__ inline float ftanh(float a){
  const float TWO_L2E = 2.8853900817779268f;
  return 1.0f - 2.0f*frcp(fexp2(TWO_L2E*a) + 1.0f);
}
__device__ inline float fsigmoid(float a){
  const float L2E = 1.4426950408889634f;
  return frcp(1.0f + fexp2(-L2E*a));
}

// ---------------- kernel 0: weights -> fused transposed f16 [N=768][K=256] ----------------
__global__ __launch_bounds__(256) void prep_kernel(const float* __restrict__ kz,
                                                   const float* __restrict__ kr,
                                                   const float* __restrict__ kh,
                                                   _Float16* __restrict__ K16T){
  int o = blockIdx.x*256 + threadIdx.x;     // 0..196607
  int n = o >> 8;                            // fused col: p*256+u
  int k = o & 255;                           // d
  int p = n >> 8;
  int u = n & 255;
  const float* w = (p==0) ? kz : ((p==1) ? kr : kh);
  K16T[o] = (_Float16)w[k*UU + u];
}

// ---------------- kernel 1: GEMM  -> P[p][b*U+u][t] (t-major, f16) ----------------
#define BM 128
#define BN 128
#define BK 32
#define LDA 40   // padded f16 row stride for As (80B: 16B aligned, bank-spread)

__global__ __launch_bounds__(256) void gemm_kernel(const float* __restrict__ X,
                                                   const _Float16* __restrict__ K16T,
                                                   const float* __restrict__ bz,
                                                   const float* __restrict__ br,
                                                   const float* __restrict__ bh,
                                                   _Float16* __restrict__ P){
  __shared__ __align__(16) _Float16 As[BM*LDA];  // 10240 B, [m][k] k-contig
  __shared__ __align__(16) _Float16 Bs[BN*BK];   // 8192 B,  [n][k] k-contig
  const int tid = threadIdx.x;
  const int bx = blockIdx.x;        // 0..5  (N tiles)
  const int by = blockIdx.y;        // 0..1023 (M tiles)
  const int rowBase = by*BM;
  const int nBase = bx*BN;

  const int wave = tid >> 6, lane = tid & 63;
  const int wm = wave & 1, wn = wave >> 1;     // 2x2 wave grid, each 64x64
  const int lrow = lane & 15, lkq = lane >> 4; // frag row / k-quad

  floatx4 acc[4][4] = {};

  // A staging: thread covers row tid>>1, 16 cols at (tid&1)*16
  const int arow = tid >> 1;
  const int acol = (tid & 1) * 16;
  const float* aptr = X + (size_t)(rowBase + arow)*DD + acol;
  _Float16* asdst = &As[arow*LDA + acol];

  for (int k0 = 0; k0 < DD; k0 += BK) {
    __syncthreads();   // protect LDS from previous iteration's readers
    // --- B tile: async global->LDS (f16, 2 x 16B per thread) ---
    #pragma unroll
    for (int i = 0; i < 2; i++) {
      int c = i*256 + tid;                 // chunk id, 512 chunks x 16B = 8KB
      const _Float16* g = K16T + (size_t)(nBase + (c>>2))*DD + k0 + (c&3)*8;
      __builtin_amdgcn_global_load_lds(
          (const __attribute__((address_space(1))) void*)g,
          (__attribute__((address_space(3))) void*)(Bs + c*8),
          16, 0, 0);
    }
    // --- A tile: fp32 load -> f16 cvt -> LDS ---
    floatx4 a0 = *(const floatx4*)(aptr + k0);
    floatx4 a1 = *(const floatx4*)(aptr + k0 + 4);
    floatx4 a2 = *(const floatx4*)(aptr + k0 + 8);
    floatx4 a3 = *(const floatx4*)(aptr + k0 + 12);
    half8 pk0, pk1;
    #pragma unroll
    for (int q = 0; q < 4; q++){
      pk0[q]   = (_Float16)a0[q];
      pk0[4+q] = (_Float16)a1[q];
      pk1[q]   = (_Float16)a2[q];
      pk1[4+q] = (_Float16)a3[q];
    }
    *(half8*)asdst       = pk0;
    *(half8*)(asdst + 8) = pk1;
    __syncthreads();
    // --- fragments + MFMA (BK=32 == one K step) ---
    half8 af[4], bf[4];
    #pragma unroll
    for (int i = 0; i < 4; i++)
      af[i] = *(const half8*)&As[(wm*64 + i*16 + lrow)*LDA + lkq*8];
    #pragma unroll
    for (int j = 0; j < 4; j++)
      bf[j] = *(const half8*)&Bs[(wn*64 + j*16 + lrow)*BK + lkq*8];
    #pragma unroll
    for (int i = 0; i < 4; i++)
      #pragma unroll
      for (int j = 0; j < 4; j++)
        acc[i][j] = __builtin_amdgcn_mfma_f32_16x16x32_f16(af[i], bf[j], acc[i][j], 0, 0, 0);
  }

  // --- epilogue: add bias, packed half4 store into t-major plane p ---
  // P[p][b*256 + u][t], t = (m % 2048). r=0..3 of each acc reg are t-consecutive.
  const int p = bx >> 1;                // plane (z/r/h); BN=128 never crosses planes
  const int ub = (bx & 1) * 128;        // u base within plane
  const float* bias = (p==0) ? bz : ((p==1) ? br : bh);
  _Float16* Pp = P + (size_t)p * PLANE;
  const int bidx = rowBase >> 11;                 // batch index (uniform per block)
  const int t0 = (rowBase & 2047) + wm*64 + lkq*4;
  #pragma unroll
  for (int j = 0; j < 4; j++){
    int col = ub + wn*64 + j*16 + lrow;           // u  (C/D: col = lane&15)
    float bv = bias[col];
    _Float16* rowp = Pp + (size_t)(bidx*UU + col)*TT + t0;
    #pragma unroll
    for (int i = 0; i < 4; i++){
      half4 v;
      #pragma unroll
      for (int r = 0; r < 4; r++)
        v[r] = (_Float16)(acc[i][j][r] + bv);     // row = quad*4+reg => t0 + i*16 + r
      *(half4*)(rowp + i*16) = v;
    }
  }
}

// ---------------- kernel 2: time scan, one lane per (b,u), t-major P ----------------
#define PF 16          // timesteps per chunk
#define NBUF 4         // register ring depth (prefetch distance 3 chunks)
__global__ __launch_bounds__(64) void scan_kernel(const _Float16* __restrict__ P,
                                                  const float* __restrict__ mz,
                                                  const float* __restrict__ mr,
                                                  float* __restrict__ out){
  const int ci = blockIdx.x*64 + threadIdx.x;   // chain id: b*256+u
  const int b = ci >> 8;
  const int u = ci & 255;
  const half8* pz = (const half8*)(P + (size_t)ci*TT);
  const half8* pr = (const half8*)(P + PLANE + (size_t)ci*TT);
  const half8* ph = (const half8*)(P + 2*PLANE + (size_t)ci*TT);
  float* po = out + (size_t)b*(TT*UU) + u;
  const float vmz = mz[u], vmr = mr[u];
  float h = 0.0f;

  half8 qz[NBUF][2], qr[NBUF][2], qh[NBUF][2];

#define LOADC(buf, c) do { \
    qz[buf][0] = pz[(c)*2];   qz[buf][1] = pz[(c)*2+1]; \
    qr[buf][0] = pr[(c)*2];   qr[buf][1] = pr[(c)*2+1]; \
    qh[buf][0] = ph[(c)*2];   qh[buf][1] = ph[(c)*2+1]; \
  } while(0)

#define PROC(buf, c) do { \
    _Pragma("unroll") \
    for (int i = 0; i < PF; i++){ \
      float xz = (float)qz[buf][i>>3][i&7]; \
      float xr = (float)qr[buf][i>>3][i&7]; \
      float xh = (float)qh[buf][i>>3][i&7]; \
      float r  = ftanh(xr + h*vmr) + 1.0f; \
      float z  = fsigmoid(xz + h*vmz); \
      float hh = ftanh(xh + r*h); \
      h = (1.0f - z)*hh + z*h; \
      po[(size_t)((c)*PF + i)*UU] = h; \
    } \
    if ((c) + NBUF < NC) LOADC(buf, (c) + NBUF); \
  } while(0)

  const int NC = TT/PF;   // 128 chunks
  LOADC(0, 0); LOADC(1, 1); LOADC(2, 2); LOADC(3, 3);
  for (int c = 0; c < NC; c += NBUF){
    PROC(0, c);
    PROC(1, c+1);
    PROC(2, c+2);
    PROC(3, c+3);
  }
#undef LOADC
#undef PROC
}

extern "C" void kernel_launch(void* const* d_in, const int* in_sizes, int n_in,
                              void* d_out, int out_size, void* d_ws, size_t ws_size,
                              hipStream_t stream) {
  (void)in_sizes; (void)n_in; (void)out_size; (void)ws_size;
  const float* x  = (const float*)d_in[0];
  const float* kz = (const float*)d_in[1];
  const float* kr = (const float*)d_in[2];
  const float* kh = (const float*)d_in[3];
  const float* mz = (const float*)d_in[4];
  const float* mr = (const float*)d_in[5];
  const float* bz = (const float*)d_in[6];
  const float* br = (const float*)d_in[7];
  const float* bh = (const float*)d_in[8];
  float* out = (float*)d_out;

  // ws layout: [K16T: 768*256 f16 = 393216 B][P: 3 planes * 33554432 f16 = 201326592 B]
  _Float16* K16T = (_Float16*)d_ws;
  _Float16* P    = (_Float16*)((char*)d_ws + 393216);

  hipLaunchKernelGGL(prep_kernel, dim3(NN*DD/256), dim3(256), 0, stream, kz, kr, kh, K16T);
  hipLaunchKernelGGL(gemm_kernel, dim3(NN/BN, MM/BM), dim3(256), 0, stream,
                     x, K16T, bz, br, bh, P);
  hipLaunchKernelGGL(scan_kernel, dim3(256), dim3(64), 0, stream, P, mz, mr, out);
}